// Round 19
// baseline (484.189 us; speedup 1.0000x reference)
//
#include <hip/hip_runtime.h>
#include <cstdint>
#include <cstddef>

// EarthAttention3D (Pangu-Weather): NW=720, L=144, DIM=192, H=6, hd=32
// All matmuls MFMA 16x16x32 bf16, split-bf16 (a = hi+lo; a*b ~= hh+hl+lh).
// Intermediates stored PACKED: one uint per element = (hi_bf16<<16)|lo_bf16.
// MFMA layouts (validated rounds 2-18): A/B row-major [m|n][k], row = lane&15,
// k = (lane>>4)*8 + t. C/D: col(n) = lane&15, row(m) = (lane>>4)*4 + reg.
//
// ROUND 19: R18 fusion + register fix. R18's spill diagnosis: 9-wave block ->
// 3 waves/SIMD -> hard budget 512/3~170 regs/wave; R17 body (~125) + pacc(48)
// = ~175 -> allocator clamped to 84 and spilled (WRITE 78->350MB). Fix (from
// R8's validated variant): split P to bf16 INSIDE the PV ks-loop, consuming
// acc pairwise -- kills the wh_/wl_[10][2] arrays (40 regs at peak). inv is
// folded into acc during phase 2. Preloads kept (R8's regression was the
// inline loads, not the split placement). Everything else == R18 (verified
// correct). Predicted peak ~135 < 170 -> no spill.

using short8 = __attribute__((ext_vector_type(8))) short;
using f32x4  = __attribute__((ext_vector_type(4))) float;

constexpr int kNW = 720;
constexpr float kScale = 0.17677669529663687f;  // 32^-0.5
constexpr size_t kQKVElems = (size_t)kNW * 6 * 144 * 32;  // 19,906,560

__device__ __forceinline__ ushort bf16_rne(float f) {
  uint u = __builtin_bit_cast(uint, f);
  return (ushort)((u + 0x7FFFu + ((u >> 16) & 1u)) >> 16);
}
__device__ __forceinline__ float bf16_to_f(ushort h) {
  uint u = ((uint)h) << 16;
  return __builtin_bit_cast(float, u);
}
__device__ __forceinline__ uint pack_hl(float f) {
  const ushort h = bf16_rne(f);
  const ushort l = bf16_rne(f - bf16_to_f(h));
  return ((uint)h << 16) | l;
}
__device__ __forceinline__ void split2(float a, float b, uint& hw, uint& lw) {
  const ushort ha = bf16_rne(a), hb = bf16_rne(b);
  const ushort la = bf16_rne(a - bf16_to_f(ha));
  const ushort lb = bf16_rne(b - bf16_to_f(hb));
  hw = (uint)ha | ((uint)hb << 16);
  lw = (uint)la | ((uint)lb << 16);
}

// ---------------------------------------------------------------------------
// prep: fp32 -> separate (hi,lo) bf16 planes (for weight panels).
// ---------------------------------------------------------------------------
__global__ __launch_bounds__(256) void prep_kernel(
    const float* __restrict__ src, ushort* __restrict__ dh,
    ushort* __restrict__ dl, int n)
{
  const int i = blockIdx.x * 256 + threadIdx.x;
  if (i < n) {
    const float f = src[i];
    const ushort h = bf16_rne(f);
    dh[i] = h;
    dl[i] = bf16_rne(f - bf16_to_f(h));
  }
}

// ---------------------------------------------------------------------------
// btT: transpose bias_table (3312,1440) -> (1440,3312); lives in dead ws.
// ---------------------------------------------------------------------------
__global__ __launch_bounds__(256) void btT_kernel(
    const float* __restrict__ bt, float* __restrict__ btT)
{
  __shared__ float T[48][49];
  const int pb = (blockIdx.x % 69) * 48;
  const int bb = (blockIdx.x / 69) * 48;
  const int tid = threadIdx.x;
  for (int f = tid; f < 2304; f += 256) {
    const int r = f / 48, c = f % 48;
    T[r][c] = bt[(size_t)(pb + r) * 1440 + bb + c];
  }
  __syncthreads();
  for (int f = tid; f < 2304; f += 256) {
    const int r = f % 48, c = f / 48;
    btT[(size_t)(bb + c) * 3312 + pb + r] = T[r][c];
  }
}

// ---------------------------------------------------------------------------
// QKV GEMM (R7 version): BM=128, BN=192, BK=32. 512 thr (8 waves, 2Mx4N).
// A and B staged in LDS. LDS 51.2 KB -> 3 blocks/CU.
// ---------------------------------------------------------------------------
__global__ __launch_bounds__(512) void qkv_gemm_kernel(
    const float* __restrict__ Xf,
    const ushort* __restrict__ Wh, const ushort* __restrict__ Wl,
    const float* __restrict__ bias,
    uint* __restrict__ qp, uint* __restrict__ kp, uint* __restrict__ vp)
{
  __shared__ ushort Ah[128][40], Al[128][40];
  __shared__ ushort Bh[192][40], Bl[192][40];

  const int bid = blockIdx.x;
  const int mtile = bid / 3;
  const int col0  = (bid % 3) * 192;
  const int row0 = mtile * 128;
  const int tid = threadIdx.x;
  const int wave = tid >> 6, lane = tid & 63;
  const int rr = lane & 15, kg = lane >> 4;
  const int wm = wave >> 2, wn = wave & 3;

  f32x4 acc[4][3];
#pragma unroll
  for (int a = 0; a < 4; ++a)
#pragma unroll
    for (int b = 0; b < 3; ++b) acc[a][b] = (f32x4){0.f, 0.f, 0.f, 0.f};

  for (int kc = 0; kc < 192; kc += 32) {
#pragma unroll
    for (int u = 0; u < 2; ++u) {
      const int sl = tid + u * 512;
      const int r = sl >> 3, s = sl & 7;
      float4 xv = *(const float4*)&Xf[(size_t)(row0 + r) * 192 + kc + s * 4];
      ushort4 hv, lv;
      hv.x = bf16_rne(xv.x); lv.x = bf16_rne(xv.x - bf16_to_f(hv.x));
      hv.y = bf16_rne(xv.y); lv.y = bf16_rne(xv.y - bf16_to_f(hv.y));
      hv.z = bf16_rne(xv.z); lv.z = bf16_rne(xv.z - bf16_to_f(hv.z));
      hv.w = bf16_rne(xv.w); lv.w = bf16_rne(xv.w - bf16_to_f(hv.w));
      *(ushort4*)&Ah[r][s * 4] = hv;
      *(ushort4*)&Al[r][s * 4] = lv;
    }
#pragma unroll
    for (int u = 0; u < 3; ++u) {
      const int idx = tid + u * 512;
      const int n = idx >> 3, s2 = idx & 7;
      const size_t g = (size_t)(col0 + n) * 192 + kc + s2 * 4;
      *(uint2*)&Bh[n][s2 * 4] = *(const uint2*)&Wh[g];
      *(uint2*)&Bl[n][s2 * 4] = *(const uint2*)&Wl[g];
    }
    __syncthreads();

    short8 ah[4], al_[4], bh[3], bl[3];
#pragma unroll
    for (int mt = 0; mt < 4; ++mt) {
      const int r = wm * 64 + mt * 16 + rr;
      ah[mt]  = *(const short8*)&Ah[r][kg * 8];
      al_[mt] = *(const short8*)&Al[r][kg * 8];
    }
#pragma unroll
    for (int nt = 0; nt < 3; ++nt) {
      const int n = wn * 48 + nt * 16 + rr;
      bh[nt] = *(const short8*)&Bh[n][kg * 8];
      bl[nt] = *(const short8*)&Bl[n][kg * 8];
    }
#pragma unroll
    for (int mt = 0; mt < 4; ++mt)
#pragma unroll
      for (int nt = 0; nt < 3; ++nt) {
        acc[mt][nt] = __builtin_amdgcn_mfma_f32_16x16x32_bf16(ah[mt],  bh[nt], acc[mt][nt], 0, 0, 0);
        acc[mt][nt] = __builtin_amdgcn_mfma_f32_16x16x32_bf16(ah[mt],  bl[nt], acc[mt][nt], 0, 0, 0);
        acc[mt][nt] = __builtin_amdgcn_mfma_f32_16x16x32_bf16(al_[mt], bh[nt], acc[mt][nt], 0, 0, 0);
      }
    __syncthreads();
  }

  const int t = col0 / 192;
  uint* dst = (t == 0) ? qp : (t == 1) ? kp : vp;
  const float sc = (t == 0) ? kScale : 1.0f;
#pragma unroll
  for (int nt = 0; nt < 3; ++nt) {
    const int c0 = wn * 48 + nt * 16;
    const int hh = c0 >> 5;
    const int d0 = (c0 & 31) + rr;
    const float bcol = bias[col0 + c0 + rr];
#pragma unroll
    for (int mt = 0; mt < 4; ++mt)
#pragma unroll
      for (int reg = 0; reg < 4; ++reg) {
        const int grow = row0 + wm * 64 + mt * 16 + kg * 4 + reg;
        const int w = grow / 144;
        const int l = grow % 144;
        dst[(((size_t)(w * 6 + hh)) * 144 + l) * 32 + d0] =
            pack_hl((acc[mt][nt][reg] + bcol) * sc);
      }
  }
}

// ---------------------------------------------------------------------------
// attn unit body + fused per-head proj partial into pacc[12].
// Register-lean: P split to bf16 inside the ks loop (no wh_/wl_ arrays).
// ---------------------------------------------------------------------------
__device__ __forceinline__ void attn_unit_fused(
    const ushort (&KsH)[144][40], const ushort (&KsL)[144][40],
    const ushort (&VtH)[32][168], const ushort (&VtL)[32][168],
    uint* __restrict__ scrw,
    const uint* __restrict__ qpb, const float* __restrict__ mrow,
    const float* __restrict__ brow,
    const ushort* __restrict__ w2h, const ushort* __restrict__ w2l,
    int u, f32x4* pacc, int wave, int rr, int kg)
{
  const int i0 = wave * 16;
  const int i = i0 + rr;
  const int pi = 828 * (i / 72) + 23 * ((i / 12) % 6) + (i % 12) + 11;

  // preloads (overlap with surrounding work)
  const uint4 qa = *(const uint4*)&qpb[(size_t)i * 32 + kg * 8];
  const uint4 qb = *(const uint4*)&qpb[(size_t)i * 32 + kg * 8 + 4];
  float4 mv[9], bv[9];
#pragma unroll
  for (int jt = 0; jt < 9; ++jt) {
    const int jb = jt * 16 + kg * 4;
    mv[jt] = *(const float4*)&mrow[(size_t)i * 144 + jb];
    const int pjb = 1656 * (jb / 72) + 138 * ((jb / 12) % 6) - (jb % 12);
    bv[jt] = *(const float4*)&brow[pi + pjb - 3];  // {bb-3,bb-2,bb-1,bb}
  }

  union { short8 v; uint uu[4]; } QH, QL;
  QH.uu[0] = (qa.x >> 16) | (qa.y & 0xffff0000u);
  QH.uu[1] = (qa.z >> 16) | (qa.w & 0xffff0000u);
  QH.uu[2] = (qb.x >> 16) | (qb.y & 0xffff0000u);
  QH.uu[3] = (qb.z >> 16) | (qb.w & 0xffff0000u);
  QL.uu[0] = (qa.x & 0xffffu) | (qa.y << 16);
  QL.uu[1] = (qa.z & 0xffffu) | (qa.w << 16);
  QL.uu[2] = (qb.x & 0xffffu) | (qb.y << 16);
  QL.uu[3] = (qb.z & 0xffffu) | (qb.w << 16);

  // Phase 1: S^T = K.Q^T + bias + mask
  f32x4 acc[9];
#pragma unroll
  for (int jt = 0; jt < 9; ++jt) {
    const short8 kah = *(const short8*)&KsH[jt * 16 + rr][kg * 8];
    const short8 kal = *(const short8*)&KsL[jt * 16 + rr][kg * 8];
    f32x4 c = (f32x4){0.f, 0.f, 0.f, 0.f};
    c = __builtin_amdgcn_mfma_f32_16x16x32_bf16(kah, QH.v, c, 0, 0, 0);
    c = __builtin_amdgcn_mfma_f32_16x16x32_bf16(kah, QL.v, c, 0, 0, 0);
    c = __builtin_amdgcn_mfma_f32_16x16x32_bf16(kal, QH.v, c, 0, 0, 0);
    c[0] += bv[jt].w + mv[jt].x;
    c[1] += bv[jt].z + mv[jt].y;
    c[2] += bv[jt].y + mv[jt].z;
    c[3] += bv[jt].x + mv[jt].w;
    acc[jt] = c;
  }

  // Phase 2: in-register softmax; normalization folded into acc
  float m = -1e30f;
#pragma unroll
  for (int jt = 0; jt < 9; ++jt)
    m = fmaxf(m, fmaxf(fmaxf(acc[jt][0], acc[jt][1]),
                       fmaxf(acc[jt][2], acc[jt][3])));
  m = fmaxf(m, __shfl_xor(m, 16));
  m = fmaxf(m, __shfl_xor(m, 32));
  float s = 0.f;
#pragma unroll
  for (int jt = 0; jt < 9; ++jt)
#pragma unroll
    for (int r = 0; r < 4; ++r) {
      acc[jt][r] = __expf(acc[jt][r] - m);
      s += acc[jt][r];
    }
  s += __shfl_xor(s, 16);
  s += __shfl_xor(s, 32);
  const float inv = 1.0f / s;
#pragma unroll
  for (int jt = 0; jt < 9; ++jt)
#pragma unroll
    for (int r = 0; r < 4; ++r) acc[jt][r] *= inv;

  // Phase 3: PV; P hi/lo split happens per-ks (register-lean, R8-validated)
  f32x4 oacc[2] = {(f32x4){0.f, 0.f, 0.f, 0.f}, (f32x4){0.f, 0.f, 0.f, 0.f}};
#pragma unroll
  for (int ks = 0; ks < 5; ++ks) {
    uint h0, h1, h2, h3, l0, l1, l2, l3;
    split2(acc[2 * ks][0], acc[2 * ks][1], h0, l0);
    split2(acc[2 * ks][2], acc[2 * ks][3], h1, l1);
    if (2 * ks + 1 < 9) {
      split2(acc[2 * ks + 1][0], acc[2 * ks + 1][1], h2, l2);
      split2(acc[2 * ks + 1][2], acc[2 * ks + 1][3], h3, l3);
    } else {
      h2 = h3 = l2 = l3 = 0;  // j in [144,160) pad
    }
    *(uint2*)&scrw[rr * 20 + 2 * kg]           = make_uint2(h0, h1);
    *(uint2*)&scrw[rr * 20 + 8 + 2 * kg]       = make_uint2(h2, h3);
    *(uint2*)&scrw[320 + rr * 20 + 2 * kg]     = make_uint2(l0, l1);
    *(uint2*)&scrw[320 + rr * 20 + 8 + 2 * kg] = make_uint2(l2, l3);
    asm volatile("s_waitcnt lgkmcnt(0)" ::: "memory");
    const ushort* scr = (const ushort*)scrw;
    const short8 pfh = *(const short8*)&scr[rr * 40 + kg * 8];
    const short8 pfl = *(const short8*)&scr[640 + rr * 40 + kg * 8];
#pragma unroll
    for (int dt = 0; dt < 2; ++dt) {
      const short8 vfh = *(const short8*)&VtH[dt * 16 + rr][ks * 32 + kg * 8];
      const short8 vfl = *(const short8*)&VtL[dt * 16 + rr][ks * 32 + kg * 8];
      oacc[dt] = __builtin_amdgcn_mfma_f32_16x16x32_bf16(pfh, vfh, oacc[dt], 0, 0, 0);
      oacc[dt] = __builtin_amdgcn_mfma_f32_16x16x32_bf16(pfh, vfl, oacc[dt], 0, 0, 0);
      oacc[dt] = __builtin_amdgcn_mfma_f32_16x16x32_bf16(pfl, vfh, oacc[dt], 0, 0, 0);
    }
    asm volatile("s_waitcnt lgkmcnt(0)" ::: "memory");
  }

  // Fused proj partial: transpose O through Scr, accumulate into pacc[12].
  {
    ushort* sh = (ushort*)scrw;
#pragma unroll
    for (int dt = 0; dt < 2; ++dt)
#pragma unroll
      for (int r = 0; r < 4; ++r) {
        const int il = kg * 4 + r;
        const int dl = dt * 16 + rr;
        const float v = oacc[dt][r];
        const ushort h = bf16_rne(v);
        sh[il * 40 + dl] = h;
        sh[640 + il * 40 + dl] = bf16_rne(v - bf16_to_f(h));
      }
    asm volatile("s_waitcnt lgkmcnt(0)" ::: "memory");
    const short8 pah = *(const short8*)&sh[rr * 40 + kg * 8];
    const short8 pal = *(const short8*)&sh[640 + rr * 40 + kg * 8];
#pragma unroll
    for (int nt = 0; nt < 12; ++nt) {
      const size_t gb = (size_t)(nt * 16 + rr) * 192 + u * 32 + kg * 8;
      const short8 wbh = *(const short8*)&w2h[gb];
      const short8 wbl = *(const short8*)&w2l[gb];
      pacc[nt] = __builtin_amdgcn_mfma_f32_16x16x32_bf16(pah, wbh, pacc[nt], 0, 0, 0);
      pacc[nt] = __builtin_amdgcn_mfma_f32_16x16x32_bf16(pah, wbl, pacc[nt], 0, 0, 0);
      pacc[nt] = __builtin_amdgcn_mfma_f32_16x16x32_bf16(pal, wbh, pacc[nt], 0, 0, 0);
    }
    asm volatile("s_waitcnt lgkmcnt(0)" ::: "memory");
  }
}

// K/V unpack-and-write helpers.
__device__ __forceinline__ void write_k(
    ushort (&KH)[144][40], ushort (&KL)[144][40], int l, int d, uint4 kv)
{
  ushort4 hk, lk;
  hk.x = (ushort)(kv.x >> 16); lk.x = (ushort)(kv.x & 0xffff);
  hk.y = (ushort)(kv.y >> 16); lk.y = (ushort)(kv.y & 0xffff);
  hk.z = (ushort)(kv.z >> 16); lk.z = (ushort)(kv.z & 0xffff);
  hk.w = (ushort)(kv.w >> 16); lk.w = (ushort)(kv.w & 0xffff);
  *(ushort4*)&KH[l][d] = hk;
  *(ushort4*)&KL[l][d] = lk;
}
__device__ __forceinline__ void write_vt(
    ushort (&VH)[32][168], ushort (&VL)[32][168], int l, int d, uint4 vv)
{
  VH[d + 0][l] = (ushort)(vv.x >> 16); VL[d + 0][l] = (ushort)(vv.x & 0xffff);
  VH[d + 1][l] = (ushort)(vv.y >> 16); VL[d + 1][l] = (ushort)(vv.y & 0xffff);
  VH[d + 2][l] = (ushort)(vv.z >> 16); VL[d + 2][l] = (ushort)(vv.z & 0xffff);
  VH[d + 3][l] = (ushort)(vv.w >> 16); VL[d + 3][l] = (ushort)(vv.w & 0xffff);
}

// ---------------------------------------------------------------------------
// attn+proj fused: 720 blocks x 576 thr. Block b -> window w=(b&7)*90+(b>>3);
// 6 heads sequential, ring of 2 K/V buffers; pacc accumulates proj across
// units; epilogue adds b2, writes fp32 out. LDS 112.1 KB.
// ---------------------------------------------------------------------------
__global__ __launch_bounds__(576) void attn_kernel(
    const uint* __restrict__ qp, const uint* __restrict__ kp,
    const uint* __restrict__ vp, const float* __restrict__ mask,
    const float* __restrict__ btT,
    const ushort* __restrict__ w2h, const ushort* __restrict__ w2l,
    const float* __restrict__ b2, float* __restrict__ out)
{
  __shared__ __align__(16) ushort Ks_[2][2][144][40];  // [buf][hi/lo]
  __shared__ __align__(16) ushort Vt[2][2][32][168];   // [buf][hi/lo][d][j]
  __shared__ __align__(16) uint Scr[9][640];           // per-wave scratch

  const int tid = threadIdx.x;
  const int wave = tid >> 6, lane = tid & 63;
  const int rr = lane & 15, kg = lane >> 4;

  const int b = blockIdx.x;
  const int w = (b & 7) * 90 + (b >> 3);   // bijective: 720 = 8*90
  const size_t base0 = (size_t)(w * 6) * 4608;
  const float* mrow = mask + (size_t)w * 20736;
  const float* brow0 = btT + (size_t)((w % 240) * 6) * 3312;
  float* out_b = out + (size_t)w * 144 * 192;

  const int l0 = tid >> 3, d0 = (tid & 7) * 4;
  const int f1 = tid + 576;
  const int l1 = f1 >> 3, d1 = (f1 & 7) * 4;

  // --- stage unit0 into buf0 ---
  {
    const uint4 kvA = *(const uint4*)&kp[base0 + l0 * 32 + d0];
    const uint4 vvA = *(const uint4*)&vp[base0 + l0 * 32 + d0];
    const uint4 kvB = *(const uint4*)&kp[base0 + l1 * 32 + d1];
    const uint4 vvB = *(const uint4*)&vp[base0 + l1 * 32 + d1];
    write_k(Ks_[0][0], Ks_[0][1], l0, d0, kvA);
    write_k(Ks_[0][0], Ks_[0][1], l1, d1, kvB);
    write_vt(Vt[0][0], Vt[0][1], l0, d0, vvA);
    write_vt(Vt[0][0], Vt[0][1], l1, d1, vvB);
  }
  // zero-pad j in [144,160) for both buffers & planes (2048 slots)
  for (int f = tid; f < 2048; f += 576) {
    const int bu = f >> 10, pl = (f >> 9) & 1, d = (f >> 4) & 31, j = 144 + (f & 15);
    Vt[bu][pl][d][j] = 0;
  }

  // proj accumulators (rows = this wave's i-strip, cols 0..191)
  f32x4 pacc[12];
#pragma unroll
  for (int nt = 0; nt < 12; ++nt) pacc[nt] = (f32x4){0.f, 0.f, 0.f, 0.f};

  // pending loads for unit1
  uint4 kA = *(const uint4*)&kp[base0 + 4608 + l0 * 32 + d0];
  uint4 vA = *(const uint4*)&vp[base0 + 4608 + l0 * 32 + d0];
  uint4 kB = *(const uint4*)&kp[base0 + 4608 + l1 * 32 + d1];
  uint4 vB = *(const uint4*)&vp[base0 + 4608 + l1 * 32 + d1];

  __syncthreads();  // buf0 ready

#pragma unroll
  for (int u = 0; u < 6; ++u) {
    attn_unit_fused(Ks_[u & 1][0], Ks_[u & 1][1], Vt[u & 1][0], Vt[u & 1][1],
                    Scr[wave], qp + base0 + (size_t)u * 4608, mrow,
                    brow0 + u * 3312, w2h, w2l, u, pacc, wave, rr, kg);
    if (u < 5) {
      write_k(Ks_[(u + 1) & 1][0], Ks_[(u + 1) & 1][1], l0, d0, kA);
      write_k(Ks_[(u + 1) & 1][0], Ks_[(u + 1) & 1][1], l1, d1, kB);
      write_vt(Vt[(u + 1) & 1][0], Vt[(u + 1) & 1][1], l0, d0, vA);
      write_vt(Vt[(u + 1) & 1][0], Vt[(u + 1) & 1][1], l1, d1, vB);
      if (u < 4) {
        kA = *(const uint4*)&kp[base0 + (size_t)(u + 2) * 4608 + l0 * 32 + d0];
        vA = *(const uint4*)&vp[base0 + (size_t)(u + 2) * 4608 + l0 * 32 + d0];
        kB = *(const uint4*)&kp[base0 + (size_t)(u + 2) * 4608 + l1 * 32 + d1];
        vB = *(const uint4*)&vp[base0 + (size_t)(u + 2) * 4608 + l1 * 32 + d1];
      }
      __syncthreads();  // next buffer ready
    }
  }

  // --- epilogue: out = pacc + b2 (fp32, coalesced 64B runs) ---
  const int i0 = wave * 16;
#pragma unroll
  for (int nt = 0; nt < 12; ++nt) {
    const int c = nt * 16 + rr;
    const float bcol = b2[c];
#pragma unroll
    for (int r = 0; r < 4; ++r)
      out_b[(size_t)(i0 + kg * 4 + r) * 192 + c] = pacc[nt][r] + bcol;
  }
}

// ---------------------------------------------------------------------------
extern "C" void kernel_launch(void* const* d_in, const int* in_sizes, int n_in,
                              void* d_out, int out_size, void* d_ws, size_t ws_size,
                              hipStream_t stream)
{
  const float* x    = (const float*)d_in[0];  // (720,144,192)
  const float* mask = (const float*)d_in[1];  // (720,144,144)
  const float* w1   = (const float*)d_in[2];  // (576,192)
  const float* b1   = (const float*)d_in[3];  // (576,)
  const float* w2   = (const float*)d_in[4];  // (192,192)
  const float* b2   = (const float*)d_in[5];  // (192,)
  const float* bt   = (const float*)d_in[6];  // (3312,240,6)
  float* out = (float*)d_out;

  // ws layout: qp/kp/vp packed-uint (3 x 79.6 MB); 4th region hosts:
  //   w1 planes at offset 0 (read by qkv, then dead),
  //   btT at float-offset 1,000,000 (19.1 MB, read by attn),
  //   w2 planes at float-offset 6,000,000 (147 KB, read by attn).
  uint* qp  = (uint*)d_ws;
  uint* kp  = qp + kQKVElems;
  uint* vp  = kp + kQKVElems;
  uint* scratch = vp + kQKVElems;  // 19,906,560 uints
  ushort* w1h = (ushort*)scratch;
  ushort* w1l = w1h + 110592;
  float* btT = (float*)scratch + 1000000;
  ushort* w2h = (ushort*)((float*)scratch + 6000000);
  ushort* w2l = w2h + 36864;

  btT_kernel<<<69 * 30, 256, 0, stream>>>(bt, btT);
  prep_kernel<<<432, 256, 0, stream>>>(w1, w1h, w1l, 110592);
  prep_kernel<<<144, 256, 0, stream>>>(w2, w2h, w2l, 36864);
  qkv_gemm_kernel<<<810 * 3, 512, 0, stream>>>(x, w1h, w1l, b1, qp, kp, vp);
  attn_kernel<<<720, 576, 0, stream>>>(qp, kp, vp, mask, btT, w2h, w2l, b2, out);
}

// Round 20
// 483.285 us; speedup vs baseline: 1.0019x; 1.0019x over previous
//
#include <hip/hip_runtime.h>
#include <cstdint>
#include <cstddef>

// EarthAttention3D (Pangu-Weather): NW=720, L=144, DIM=192, H=6, hd=32
// All matmuls MFMA 16x16x32 bf16, split-bf16 (a = hi+lo; a*b ~= hh+hl+lh).
// Intermediates stored PACKED: one uint per element = (hi_bf16<<16)|lo_bf16.
// MFMA layouts (validated rounds 2-19): A/B row-major [m|n][k], row = lane&15,
// k = (lane>>4)*8 + t. C/D: col(n) = lane&15, row(m) = (lane>>4)*4 + reg.
//
// ROUND 20: R19 fusion + __launch_bounds__(576, 3) on attn. Diagnosis: both
// R18/R19 clamped at VGPR=84 ~ 512/6 -> the compiler targets 6 waves/SIMD by
// default and SPILLS the fused kernel to meet it (WRITE 78->350MB). A 9-wave
// block packs {3,2,2,2}/SIMD, so the true constraint is 3 waves/SIMD ->
// budget 170 regs. (576,3) requests exactly that. (R6's regression was this
// knob used the WRONG direction: (512,6) shrank the budget.) Source otherwise
// byte-identical to R19 (fusion twice-verified correct).

using short8 = __attribute__((ext_vector_type(8))) short;
using f32x4  = __attribute__((ext_vector_type(4))) float;

constexpr int kNW = 720;
constexpr float kScale = 0.17677669529663687f;  // 32^-0.5
constexpr size_t kQKVElems = (size_t)kNW * 6 * 144 * 32;  // 19,906,560

__device__ __forceinline__ ushort bf16_rne(float f) {
  uint u = __builtin_bit_cast(uint, f);
  return (ushort)((u + 0x7FFFu + ((u >> 16) & 1u)) >> 16);
}
__device__ __forceinline__ float bf16_to_f(ushort h) {
  uint u = ((uint)h) << 16;
  return __builtin_bit_cast(float, u);
}
__device__ __forceinline__ uint pack_hl(float f) {
  const ushort h = bf16_rne(f);
  const ushort l = bf16_rne(f - bf16_to_f(h));
  return ((uint)h << 16) | l;
}
__device__ __forceinline__ void split2(float a, float b, uint& hw, uint& lw) {
  const ushort ha = bf16_rne(a), hb = bf16_rne(b);
  const ushort la = bf16_rne(a - bf16_to_f(ha));
  const ushort lb = bf16_rne(b - bf16_to_f(hb));
  hw = (uint)ha | ((uint)hb << 16);
  lw = (uint)la | ((uint)lb << 16);
}

// ---------------------------------------------------------------------------
// prep: fp32 -> separate (hi,lo) bf16 planes (for weight panels).
// ---------------------------------------------------------------------------
__global__ __launch_bounds__(256) void prep_kernel(
    const float* __restrict__ src, ushort* __restrict__ dh,
    ushort* __restrict__ dl, int n)
{
  const int i = blockIdx.x * 256 + threadIdx.x;
  if (i < n) {
    const float f = src[i];
    const ushort h = bf16_rne(f);
    dh[i] = h;
    dl[i] = bf16_rne(f - bf16_to_f(h));
  }
}

// ---------------------------------------------------------------------------
// btT: transpose bias_table (3312,1440) -> (1440,3312); lives in dead ws.
// ---------------------------------------------------------------------------
__global__ __launch_bounds__(256) void btT_kernel(
    const float* __restrict__ bt, float* __restrict__ btT)
{
  __shared__ float T[48][49];
  const int pb = (blockIdx.x % 69) * 48;
  const int bb = (blockIdx.x / 69) * 48;
  const int tid = threadIdx.x;
  for (int f = tid; f < 2304; f += 256) {
    const int r = f / 48, c = f % 48;
    T[r][c] = bt[(size_t)(pb + r) * 1440 + bb + c];
  }
  __syncthreads();
  for (int f = tid; f < 2304; f += 256) {
    const int r = f % 48, c = f / 48;
    btT[(size_t)(bb + c) * 3312 + pb + r] = T[r][c];
  }
}

// ---------------------------------------------------------------------------
// QKV GEMM (R7 version): BM=128, BN=192, BK=32. 512 thr (8 waves, 2Mx4N).
// A and B staged in LDS. LDS 51.2 KB -> 3 blocks/CU.
// ---------------------------------------------------------------------------
__global__ __launch_bounds__(512) void qkv_gemm_kernel(
    const float* __restrict__ Xf,
    const ushort* __restrict__ Wh, const ushort* __restrict__ Wl,
    const float* __restrict__ bias,
    uint* __restrict__ qp, uint* __restrict__ kp, uint* __restrict__ vp)
{
  __shared__ ushort Ah[128][40], Al[128][40];
  __shared__ ushort Bh[192][40], Bl[192][40];

  const int bid = blockIdx.x;
  const int mtile = bid / 3;
  const int col0  = (bid % 3) * 192;
  const int row0 = mtile * 128;
  const int tid = threadIdx.x;
  const int wave = tid >> 6, lane = tid & 63;
  const int rr = lane & 15, kg = lane >> 4;
  const int wm = wave >> 2, wn = wave & 3;

  f32x4 acc[4][3];
#pragma unroll
  for (int a = 0; a < 4; ++a)
#pragma unroll
    for (int b = 0; b < 3; ++b) acc[a][b] = (f32x4){0.f, 0.f, 0.f, 0.f};

  for (int kc = 0; kc < 192; kc += 32) {
#pragma unroll
    for (int u = 0; u < 2; ++u) {
      const int sl = tid + u * 512;
      const int r = sl >> 3, s = sl & 7;
      float4 xv = *(const float4*)&Xf[(size_t)(row0 + r) * 192 + kc + s * 4];
      ushort4 hv, lv;
      hv.x = bf16_rne(xv.x); lv.x = bf16_rne(xv.x - bf16_to_f(hv.x));
      hv.y = bf16_rne(xv.y); lv.y = bf16_rne(xv.y - bf16_to_f(hv.y));
      hv.z = bf16_rne(xv.z); lv.z = bf16_rne(xv.z - bf16_to_f(hv.z));
      hv.w = bf16_rne(xv.w); lv.w = bf16_rne(xv.w - bf16_to_f(hv.w));
      *(ushort4*)&Ah[r][s * 4] = hv;
      *(ushort4*)&Al[r][s * 4] = lv;
    }
#pragma unroll
    for (int u = 0; u < 3; ++u) {
      const int idx = tid + u * 512;
      const int n = idx >> 3, s2 = idx & 7;
      const size_t g = (size_t)(col0 + n) * 192 + kc + s2 * 4;
      *(uint2*)&Bh[n][s2 * 4] = *(const uint2*)&Wh[g];
      *(uint2*)&Bl[n][s2 * 4] = *(const uint2*)&Wl[g];
    }
    __syncthreads();

    short8 ah[4], al_[4], bh[3], bl[3];
#pragma unroll
    for (int mt = 0; mt < 4; ++mt) {
      const int r = wm * 64 + mt * 16 + rr;
      ah[mt]  = *(const short8*)&Ah[r][kg * 8];
      al_[mt] = *(const short8*)&Al[r][kg * 8];
    }
#pragma unroll
    for (int nt = 0; nt < 3; ++nt) {
      const int n = wn * 48 + nt * 16 + rr;
      bh[nt] = *(const short8*)&Bh[n][kg * 8];
      bl[nt] = *(const short8*)&Bl[n][kg * 8];
    }
#pragma unroll
    for (int mt = 0; mt < 4; ++mt)
#pragma unroll
      for (int nt = 0; nt < 3; ++nt) {
        acc[mt][nt] = __builtin_amdgcn_mfma_f32_16x16x32_bf16(ah[mt],  bh[nt], acc[mt][nt], 0, 0, 0);
        acc[mt][nt] = __builtin_amdgcn_mfma_f32_16x16x32_bf16(ah[mt],  bl[nt], acc[mt][nt], 0, 0, 0);
        acc[mt][nt] = __builtin_amdgcn_mfma_f32_16x16x32_bf16(al_[mt], bh[nt], acc[mt][nt], 0, 0, 0);
      }
    __syncthreads();
  }

  const int t = col0 / 192;
  uint* dst = (t == 0) ? qp : (t == 1) ? kp : vp;
  const float sc = (t == 0) ? kScale : 1.0f;
#pragma unroll
  for (int nt = 0; nt < 3; ++nt) {
    const int c0 = wn * 48 + nt * 16;
    const int hh = c0 >> 5;
    const int d0 = (c0 & 31) + rr;
    const float bcol = bias[col0 + c0 + rr];
#pragma unroll
    for (int mt = 0; mt < 4; ++mt)
#pragma unroll
      for (int reg = 0; reg < 4; ++reg) {
        const int grow = row0 + wm * 64 + mt * 16 + kg * 4 + reg;
        const int w = grow / 144;
        const int l = grow % 144;
        dst[(((size_t)(w * 6 + hh)) * 144 + l) * 32 + d0] =
            pack_hl((acc[mt][nt][reg] + bcol) * sc);
      }
  }
}

// ---------------------------------------------------------------------------
// attn unit body + fused per-head proj partial into pacc[12].
// ---------------------------------------------------------------------------
__device__ __forceinline__ void attn_unit_fused(
    const ushort (&KsH)[144][40], const ushort (&KsL)[144][40],
    const ushort (&VtH)[32][168], const ushort (&VtL)[32][168],
    uint* __restrict__ scrw,
    const uint* __restrict__ qpb, const float* __restrict__ mrow,
    const float* __restrict__ brow,
    const ushort* __restrict__ w2h, const ushort* __restrict__ w2l,
    int u, f32x4* pacc, int wave, int rr, int kg)
{
  const int i0 = wave * 16;
  const int i = i0 + rr;
  const int pi = 828 * (i / 72) + 23 * ((i / 12) % 6) + (i % 12) + 11;

  // preloads (overlap with surrounding work)
  const uint4 qa = *(const uint4*)&qpb[(size_t)i * 32 + kg * 8];
  const uint4 qb = *(const uint4*)&qpb[(size_t)i * 32 + kg * 8 + 4];
  float4 mv[9], bv[9];
#pragma unroll
  for (int jt = 0; jt < 9; ++jt) {
    const int jb = jt * 16 + kg * 4;
    mv[jt] = *(const float4*)&mrow[(size_t)i * 144 + jb];
    const int pjb = 1656 * (jb / 72) + 138 * ((jb / 12) % 6) - (jb % 12);
    bv[jt] = *(const float4*)&brow[pi + pjb - 3];  // {bb-3,bb-2,bb-1,bb}
  }

  union { short8 v; uint uu[4]; } QH, QL;
  QH.uu[0] = (qa.x >> 16) | (qa.y & 0xffff0000u);
  QH.uu[1] = (qa.z >> 16) | (qa.w & 0xffff0000u);
  QH.uu[2] = (qb.x >> 16) | (qb.y & 0xffff0000u);
  QH.uu[3] = (qb.z >> 16) | (qb.w & 0xffff0000u);
  QL.uu[0] = (qa.x & 0xffffu) | (qa.y << 16);
  QL.uu[1] = (qa.z & 0xffffu) | (qa.w << 16);
  QL.uu[2] = (qb.x & 0xffffu) | (qb.y << 16);
  QL.uu[3] = (qb.z & 0xffffu) | (qb.w << 16);

  // Phase 1: S^T = K.Q^T + bias + mask
  f32x4 acc[9];
#pragma unroll
  for (int jt = 0; jt < 9; ++jt) {
    const short8 kah = *(const short8*)&KsH[jt * 16 + rr][kg * 8];
    const short8 kal = *(const short8*)&KsL[jt * 16 + rr][kg * 8];
    f32x4 c = (f32x4){0.f, 0.f, 0.f, 0.f};
    c = __builtin_amdgcn_mfma_f32_16x16x32_bf16(kah, QH.v, c, 0, 0, 0);
    c = __builtin_amdgcn_mfma_f32_16x16x32_bf16(kah, QL.v, c, 0, 0, 0);
    c = __builtin_amdgcn_mfma_f32_16x16x32_bf16(kal, QH.v, c, 0, 0, 0);
    c[0] += bv[jt].w + mv[jt].x;
    c[1] += bv[jt].z + mv[jt].y;
    c[2] += bv[jt].y + mv[jt].z;
    c[3] += bv[jt].x + mv[jt].w;
    acc[jt] = c;
  }

  // Phase 2: in-register softmax; normalization folded into acc
  float m = -1e30f;
#pragma unroll
  for (int jt = 0; jt < 9; ++jt)
    m = fmaxf(m, fmaxf(fmaxf(acc[jt][0], acc[jt][1]),
                       fmaxf(acc[jt][2], acc[jt][3])));
  m = fmaxf(m, __shfl_xor(m, 16));
  m = fmaxf(m, __shfl_xor(m, 32));
  float s = 0.f;
#pragma unroll
  for (int jt = 0; jt < 9; ++jt)
#pragma unroll
    for (int r = 0; r < 4; ++r) {
      acc[jt][r] = __expf(acc[jt][r] - m);
      s += acc[jt][r];
    }
  s += __shfl_xor(s, 16);
  s += __shfl_xor(s, 32);
  const float inv = 1.0f / s;
#pragma unroll
  for (int jt = 0; jt < 9; ++jt)
#pragma unroll
    for (int r = 0; r < 4; ++r) acc[jt][r] *= inv;

  // Phase 3: PV; P hi/lo split per-ks (register-lean)
  f32x4 oacc[2] = {(f32x4){0.f, 0.f, 0.f, 0.f}, (f32x4){0.f, 0.f, 0.f, 0.f}};
#pragma unroll
  for (int ks = 0; ks < 5; ++ks) {
    uint h0, h1, h2, h3, l0, l1, l2, l3;
    split2(acc[2 * ks][0], acc[2 * ks][1], h0, l0);
    split2(acc[2 * ks][2], acc[2 * ks][3], h1, l1);
    if (2 * ks + 1 < 9) {
      split2(acc[2 * ks + 1][0], acc[2 * ks + 1][1], h2, l2);
      split2(acc[2 * ks + 1][2], acc[2 * ks + 1][3], h3, l3);
    } else {
      h2 = h3 = l2 = l3 = 0;  // j in [144,160) pad
    }
    *(uint2*)&scrw[rr * 20 + 2 * kg]           = make_uint2(h0, h1);
    *(uint2*)&scrw[rr * 20 + 8 + 2 * kg]       = make_uint2(h2, h3);
    *(uint2*)&scrw[320 + rr * 20 + 2 * kg]     = make_uint2(l0, l1);
    *(uint2*)&scrw[320 + rr * 20 + 8 + 2 * kg] = make_uint2(l2, l3);
    asm volatile("s_waitcnt lgkmcnt(0)" ::: "memory");
    const ushort* scr = (const ushort*)scrw;
    const short8 pfh = *(const short8*)&scr[rr * 40 + kg * 8];
    const short8 pfl = *(const short8*)&scr[640 + rr * 40 + kg * 8];
#pragma unroll
    for (int dt = 0; dt < 2; ++dt) {
      const short8 vfh = *(const short8*)&VtH[dt * 16 + rr][ks * 32 + kg * 8];
      const short8 vfl = *(const short8*)&VtL[dt * 16 + rr][ks * 32 + kg * 8];
      oacc[dt] = __builtin_amdgcn_mfma_f32_16x16x32_bf16(pfh, vfh, oacc[dt], 0, 0, 0);
      oacc[dt] = __builtin_amdgcn_mfma_f32_16x16x32_bf16(pfh, vfl, oacc[dt], 0, 0, 0);
      oacc[dt] = __builtin_amdgcn_mfma_f32_16x16x32_bf16(pfl, vfh, oacc[dt], 0, 0, 0);
    }
    asm volatile("s_waitcnt lgkmcnt(0)" ::: "memory");
  }

  // Fused proj partial: transpose O through Scr, accumulate into pacc[12].
  {
    ushort* sh = (ushort*)scrw;
#pragma unroll
    for (int dt = 0; dt < 2; ++dt)
#pragma unroll
      for (int r = 0; r < 4; ++r) {
        const int il = kg * 4 + r;
        const int dl = dt * 16 + rr;
        const float v = oacc[dt][r];
        const ushort h = bf16_rne(v);
        sh[il * 40 + dl] = h;
        sh[640 + il * 40 + dl] = bf16_rne(v - bf16_to_f(h));
      }
    asm volatile("s_waitcnt lgkmcnt(0)" ::: "memory");
    const short8 pah = *(const short8*)&sh[rr * 40 + kg * 8];
    const short8 pal = *(const short8*)&sh[640 + rr * 40 + kg * 8];
#pragma unroll
    for (int nt = 0; nt < 12; ++nt) {
      const size_t gb = (size_t)(nt * 16 + rr) * 192 + u * 32 + kg * 8;
      const short8 wbh = *(const short8*)&w2h[gb];
      const short8 wbl = *(const short8*)&w2l[gb];
      pacc[nt] = __builtin_amdgcn_mfma_f32_16x16x32_bf16(pah, wbh, pacc[nt], 0, 0, 0);
      pacc[nt] = __builtin_amdgcn_mfma_f32_16x16x32_bf16(pah, wbl, pacc[nt], 0, 0, 0);
      pacc[nt] = __builtin_amdgcn_mfma_f32_16x16x32_bf16(pal, wbh, pacc[nt], 0, 0, 0);
    }
    asm volatile("s_waitcnt lgkmcnt(0)" ::: "memory");
  }
}

// K/V unpack-and-write helpers.
__device__ __forceinline__ void write_k(
    ushort (&KH)[144][40], ushort (&KL)[144][40], int l, int d, uint4 kv)
{
  ushort4 hk, lk;
  hk.x = (ushort)(kv.x >> 16); lk.x = (ushort)(kv.x & 0xffff);
  hk.y = (ushort)(kv.y >> 16); lk.y = (ushort)(kv.y & 0xffff);
  hk.z = (ushort)(kv.z >> 16); lk.z = (ushort)(kv.z & 0xffff);
  hk.w = (ushort)(kv.w >> 16); lk.w = (ushort)(kv.w & 0xffff);
  *(ushort4*)&KH[l][d] = hk;
  *(ushort4*)&KL[l][d] = lk;
}
__device__ __forceinline__ void write_vt(
    ushort (&VH)[32][168], ushort (&VL)[32][168], int l, int d, uint4 vv)
{
  VH[d + 0][l] = (ushort)(vv.x >> 16); VL[d + 0][l] = (ushort)(vv.x & 0xffff);
  VH[d + 1][l] = (ushort)(vv.y >> 16); VL[d + 1][l] = (ushort)(vv.y & 0xffff);
  VH[d + 2][l] = (ushort)(vv.z >> 16); VL[d + 2][l] = (ushort)(vv.z & 0xffff);
  VH[d + 3][l] = (ushort)(vv.w >> 16); VL[d + 3][l] = (ushort)(vv.w & 0xffff);
}

// ---------------------------------------------------------------------------
// attn+proj fused: 720 blocks x 576 thr. Block b -> window w=(b&7)*90+(b>>3);
// 6 heads sequential, ring of 2 K/V buffers; pacc accumulates proj across
// units; epilogue adds b2, writes fp32 out. LDS 112.1 KB.
// __launch_bounds__(576, 3): 9 waves pack {3,2,2,2}/SIMD -> per-wave budget
// 512/3 = 170 regs; the default (no hint) targeted 6 waves/SIMD (84) & spilt.
// ---------------------------------------------------------------------------
__global__ __launch_bounds__(576, 3) void attn_kernel(
    const uint* __restrict__ qp, const uint* __restrict__ kp,
    const uint* __restrict__ vp, const float* __restrict__ mask,
    const float* __restrict__ btT,
    const ushort* __restrict__ w2h, const ushort* __restrict__ w2l,
    const float* __restrict__ b2, float* __restrict__ out)
{
  __shared__ __align__(16) ushort Ks_[2][2][144][40];  // [buf][hi/lo]
  __shared__ __align__(16) ushort Vt[2][2][32][168];   // [buf][hi/lo][d][j]
  __shared__ __align__(16) uint Scr[9][640];           // per-wave scratch

  const int tid = threadIdx.x;
  const int wave = tid >> 6, lane = tid & 63;
  const int rr = lane & 15, kg = lane >> 4;

  const int b = blockIdx.x;
  const int w = (b & 7) * 90 + (b >> 3);   // bijective: 720 = 8*90
  const size_t base0 = (size_t)(w * 6) * 4608;
  const float* mrow = mask + (size_t)w * 20736;
  const float* brow0 = btT + (size_t)((w % 240) * 6) * 3312;
  float* out_b = out + (size_t)w * 144 * 192;

  const int l0 = tid >> 3, d0 = (tid & 7) * 4;
  const int f1 = tid + 576;
  const int l1 = f1 >> 3, d1 = (f1 & 7) * 4;

  // --- stage unit0 into buf0 ---
  {
    const uint4 kvA = *(const uint4*)&kp[base0 + l0 * 32 + d0];
    const uint4 vvA = *(const uint4*)&vp[base0 + l0 * 32 + d0];
    const uint4 kvB = *(const uint4*)&kp[base0 + l1 * 32 + d1];
    const uint4 vvB = *(const uint4*)&vp[base0 + l1 * 32 + d1];
    write_k(Ks_[0][0], Ks_[0][1], l0, d0, kvA);
    write_k(Ks_[0][0], Ks_[0][1], l1, d1, kvB);
    write_vt(Vt[0][0], Vt[0][1], l0, d0, vvA);
    write_vt(Vt[0][0], Vt[0][1], l1, d1, vvB);
  }
  // zero-pad j in [144,160) for both buffers & planes (2048 slots)
  for (int f = tid; f < 2048; f += 576) {
    const int bu = f >> 10, pl = (f >> 9) & 1, d = (f >> 4) & 31, j = 144 + (f & 15);
    Vt[bu][pl][d][j] = 0;
  }

  // proj accumulators (rows = this wave's i-strip, cols 0..191)
  f32x4 pacc[12];
#pragma unroll
  for (int nt = 0; nt < 12; ++nt) pacc[nt] = (f32x4){0.f, 0.f, 0.f, 0.f};

  // pending loads for unit1
  uint4 kA = *(const uint4*)&kp[base0 + 4608 + l0 * 32 + d0];
  uint4 vA = *(const uint4*)&vp[base0 + 4608 + l0 * 32 + d0];
  uint4 kB = *(const uint4*)&kp[base0 + 4608 + l1 * 32 + d1];
  uint4 vB = *(const uint4*)&vp[base0 + 4608 + l1 * 32 + d1];

  __syncthreads();  // buf0 ready

#pragma unroll
  for (int u = 0; u < 6; ++u) {
    attn_unit_fused(Ks_[u & 1][0], Ks_[u & 1][1], Vt[u & 1][0], Vt[u & 1][1],
                    Scr[wave], qp + base0 + (size_t)u * 4608, mrow,
                    brow0 + u * 3312, w2h, w2l, u, pacc, wave, rr, kg);
    if (u < 5) {
      write_k(Ks_[(u + 1) & 1][0], Ks_[(u + 1) & 1][1], l0, d0, kA);
      write_k(Ks_[(u + 1) & 1][0], Ks_[(u + 1) & 1][1], l1, d1, kB);
      write_vt(Vt[(u + 1) & 1][0], Vt[(u + 1) & 1][1], l0, d0, vA);
      write_vt(Vt[(u + 1) & 1][0], Vt[(u + 1) & 1][1], l1, d1, vB);
      if (u < 4) {
        kA = *(const uint4*)&kp[base0 + (size_t)(u + 2) * 4608 + l0 * 32 + d0];
        vA = *(const uint4*)&vp[base0 + (size_t)(u + 2) * 4608 + l0 * 32 + d0];
        kB = *(const uint4*)&kp[base0 + (size_t)(u + 2) * 4608 + l1 * 32 + d1];
        vB = *(const uint4*)&vp[base0 + (size_t)(u + 2) * 4608 + l1 * 32 + d1];
      }
      __syncthreads();  // next buffer ready
    }
  }

  // --- epilogue: out = pacc + b2 (fp32, coalesced 64B runs) ---
  const int i0 = wave * 16;
#pragma unroll
  for (int nt = 0; nt < 12; ++nt) {
    const int c = nt * 16 + rr;
    const float bcol = b2[c];
#pragma unroll
    for (int r = 0; r < 4; ++r)
      out_b[(size_t)(i0 + kg * 4 + r) * 192 + c] = pacc[nt][r] + bcol;
  }
}

// ---------------------------------------------------------------------------
extern "C" void kernel_launch(void* const* d_in, const int* in_sizes, int n_in,
                              void* d_out, int out_size, void* d_ws, size_t ws_size,
                              hipStream_t stream)
{
  const float* x    = (const float*)d_in[0];  // (720,144,192)
  const float* mask = (const float*)d_in[1];  // (720,144,144)
  const float* w1   = (const float*)d_in[2];  // (576,192)
  const float* b1   = (const float*)d_in[3];  // (576,)
  const float* w2   = (const float*)d_in[4];  // (192,192)
  const float* b2   = (const float*)d_in[5];  // (192,)
  const float* bt   = (const float*)d_in[6];  // (3312,240,6)
  float* out = (float*)d_out;

  // ws layout: qp/kp/vp packed-uint (3 x 79.6 MB); 4th region hosts:
  //   w1 planes at offset 0 (read by qkv, then dead),
  //   btT at float-offset 1,000,000 (19.1 MB, read by attn),
  //   w2 planes at float-offset 6,000,000 (147 KB, read by attn).
  uint* qp  = (uint*)d_ws;
  uint* kp  = qp + kQKVElems;
  uint* vp  = kp + kQKVElems;
  uint* scratch = vp + kQKVElems;  // 19,906,560 uints
  ushort* w1h = (ushort*)scratch;
  ushort* w1l = w1h + 110592;
  float* btT = (float*)scratch + 1000000;
  ushort* w2h = (ushort*)((float*)scratch + 6000000);
  ushort* w2l = w2h + 36864;

  btT_kernel<<<69 * 30, 256, 0, stream>>>(bt, btT);
  prep_kernel<<<432, 256, 0, stream>>>(w1, w1h, w1l, 110592);
  prep_kernel<<<144, 256, 0, stream>>>(w2, w2h, w2l, 36864);
  qkv_gemm_kernel<<<810 * 3, 512, 0, stream>>>(x, w1h, w1l, b1, qp, kp, vp);
  attn_kernel<<<720, 576, 0, stream>>>(qp, kp, vp, mask, btT, w2h, w2l, b2, out);
}

// Round 21
// 357.851 us; speedup vs baseline: 1.3530x; 1.3505x over previous
//
#include <hip/hip_runtime.h>
#include <cstdint>
#include <cstddef>

// EarthAttention3D (Pangu-Weather): NW=720, L=144, DIM=192, H=6, hd=32
// All matmuls MFMA 16x16x32 bf16, split-bf16 (a = hi+lo; a*b ~= hh+hl+lh).
// Intermediates stored PACKED: one uint per element = (hi_bf16<<16)|lo_bf16.
// MFMA layouts (validated rounds 2-20): A/B row-major [m|n][k], row = lane&15,
// k = (lane>>4)*8 + t. C/D: col(n) = lane&15, row(m) = (lane>>4)*4 + reg.
//
// ROUND 21 = R17 verbatim (measured best: 358.7 us). The attn+proj fusion
// (R18-R20) is structurally register-infeasible: phase-1 peak live state
// (mv/bv 72 + acc 36 + pacc 48 + Q/addr ~28 = ~184) exceeds even the
// 3-waves/SIMD budget (170); the allocator spills ~350 MB no matter what
// launch_bounds requests. Reverting to the proven pipeline:
//   btT + prep(w1) -> qkv GEMM -> attn (3-head sequential ring, T14 staging)
//   -> prep(w2) -> proj GEMM.

using short8 = __attribute__((ext_vector_type(8))) short;
using f32x4  = __attribute__((ext_vector_type(4))) float;

constexpr int kNW = 720;
constexpr float kScale = 0.17677669529663687f;  // 32^-0.5
constexpr size_t kQKVElems = (size_t)kNW * 6 * 144 * 32;  // 19,906,560

__device__ __forceinline__ ushort bf16_rne(float f) {
  uint u = __builtin_bit_cast(uint, f);
  return (ushort)((u + 0x7FFFu + ((u >> 16) & 1u)) >> 16);
}
__device__ __forceinline__ float bf16_to_f(ushort h) {
  uint u = ((uint)h) << 16;
  return __builtin_bit_cast(float, u);
}
__device__ __forceinline__ uint pack_hl(float f) {
  const ushort h = bf16_rne(f);
  const ushort l = bf16_rne(f - bf16_to_f(h));
  return ((uint)h << 16) | l;
}

// ---------------------------------------------------------------------------
// prep: fp32 -> separate (hi,lo) bf16 planes (for weight panels).
// ---------------------------------------------------------------------------
__global__ __launch_bounds__(256) void prep_kernel(
    const float* __restrict__ src, ushort* __restrict__ dh,
    ushort* __restrict__ dl, int n)
{
  const int i = blockIdx.x * 256 + threadIdx.x;
  if (i < n) {
    const float f = src[i];
    const ushort h = bf16_rne(f);
    dh[i] = h;
    dl[i] = bf16_rne(f - bf16_to_f(h));
  }
}

// ---------------------------------------------------------------------------
// btT: transpose bias_table (3312,1440) -> (1440,3312); lives in dead d_out.
// ---------------------------------------------------------------------------
__global__ __launch_bounds__(256) void btT_kernel(
    const float* __restrict__ bt, float* __restrict__ btT)
{
  __shared__ float T[48][49];
  const int pb = (blockIdx.x % 69) * 48;
  const int bb = (blockIdx.x / 69) * 48;
  const int tid = threadIdx.x;
  for (int f = tid; f < 2304; f += 256) {
    const int r = f / 48, c = f % 48;
    T[r][c] = bt[(size_t)(pb + r) * 1440 + bb + c];
  }
  __syncthreads();
  for (int f = tid; f < 2304; f += 256) {
    const int r = f % 48, c = f / 48;
    btT[(size_t)(bb + c) * 3312 + pb + r] = T[r][c];
  }
}

// ---------------------------------------------------------------------------
// GEMM (R7 version): out[M,N] = X[M,192] @ W[N,192]^T + bias. BM=128, BN=192,
// BK=32. 512 thr (8 waves, 2Mx4N): wave computes 64x48 = 4(m) x 3(n) tiles.
// A and B staged in LDS. LDS 51.2 KB -> 3 blocks/CU.
// ---------------------------------------------------------------------------
template <bool IS_QKV>
__global__ __launch_bounds__(512) void gemm_kernel(
    const float* __restrict__ Xf, const uint* __restrict__ Xp,
    const ushort* __restrict__ Wh, const ushort* __restrict__ Wl,
    const float* __restrict__ bias,
    uint* __restrict__ qp, uint* __restrict__ kp, uint* __restrict__ vp,
    float* __restrict__ fout)
{
  __shared__ ushort Ah[128][40], Al[128][40];
  __shared__ ushort Bh[192][40], Bl[192][40];

  const int bid = blockIdx.x;
  const int mtile = IS_QKV ? bid / 3 : bid;
  const int col0  = IS_QKV ? (bid % 3) * 192 : 0;
  const int row0 = mtile * 128;
  const int tid = threadIdx.x;
  const int wave = tid >> 6, lane = tid & 63;
  const int rr = lane & 15, kg = lane >> 4;
  const int wm = wave >> 2, wn = wave & 3;

  f32x4 acc[4][3];
#pragma unroll
  for (int a = 0; a < 4; ++a)
#pragma unroll
    for (int b = 0; b < 3; ++b) acc[a][b] = (f32x4){0.f, 0.f, 0.f, 0.f};

  for (int kc = 0; kc < 192; kc += 32) {
    // A: 128 rows x 32 k = 1024 4-elem slots, 2/thread
#pragma unroll
    for (int u = 0; u < 2; ++u) {
      const int sl = tid + u * 512;
      const int r = sl >> 3, s = sl & 7;
      if constexpr (IS_QKV) {
        float4 xv = *(const float4*)&Xf[(size_t)(row0 + r) * 192 + kc + s * 4];
        ushort4 hv, lv;
        hv.x = bf16_rne(xv.x); lv.x = bf16_rne(xv.x - bf16_to_f(hv.x));
        hv.y = bf16_rne(xv.y); lv.y = bf16_rne(xv.y - bf16_to_f(hv.y));
        hv.z = bf16_rne(xv.z); lv.z = bf16_rne(xv.z - bf16_to_f(hv.z));
        hv.w = bf16_rne(xv.w); lv.w = bf16_rne(xv.w - bf16_to_f(hv.w));
        *(ushort4*)&Ah[r][s * 4] = hv;
        *(ushort4*)&Al[r][s * 4] = lv;
      } else {
        uint4 a = *(const uint4*)&Xp[(size_t)(row0 + r) * 192 + kc + s * 4];
        uint2 hh, ll;
        hh.x = (a.x >> 16) | (a.y & 0xffff0000u);
        hh.y = (a.z >> 16) | (a.w & 0xffff0000u);
        ll.x = (a.x & 0xffffu) | (a.y << 16);
        ll.y = (a.z & 0xffffu) | (a.w << 16);
        *(uint2*)&Ah[r][s * 4] = hh;
        *(uint2*)&Al[r][s * 4] = ll;
      }
    }
    // B: 192 rows x 32 k per plane = 1536 uint2 slots/plane, 3+3 per thread
#pragma unroll
    for (int u = 0; u < 3; ++u) {
      const int idx = tid + u * 512;
      const int n = idx >> 3, s2 = idx & 7;
      const size_t g = (size_t)(col0 + n) * 192 + kc + s2 * 4;
      *(uint2*)&Bh[n][s2 * 4] = *(const uint2*)&Wh[g];
      *(uint2*)&Bl[n][s2 * 4] = *(const uint2*)&Wl[g];
    }
    __syncthreads();

    short8 ah[4], al_[4], bh[3], bl[3];
#pragma unroll
    for (int mt = 0; mt < 4; ++mt) {
      const int r = wm * 64 + mt * 16 + rr;
      ah[mt]  = *(const short8*)&Ah[r][kg * 8];
      al_[mt] = *(const short8*)&Al[r][kg * 8];
    }
#pragma unroll
    for (int nt = 0; nt < 3; ++nt) {
      const int n = wn * 48 + nt * 16 + rr;
      bh[nt] = *(const short8*)&Bh[n][kg * 8];
      bl[nt] = *(const short8*)&Bl[n][kg * 8];
    }
#pragma unroll
    for (int mt = 0; mt < 4; ++mt)
#pragma unroll
      for (int nt = 0; nt < 3; ++nt) {
        acc[mt][nt] = __builtin_amdgcn_mfma_f32_16x16x32_bf16(ah[mt],  bh[nt], acc[mt][nt], 0, 0, 0);
        acc[mt][nt] = __builtin_amdgcn_mfma_f32_16x16x32_bf16(ah[mt],  bl[nt], acc[mt][nt], 0, 0, 0);
        acc[mt][nt] = __builtin_amdgcn_mfma_f32_16x16x32_bf16(al_[mt], bh[nt], acc[mt][nt], 0, 0, 0);
      }
    __syncthreads();
  }

  if (IS_QKV) {
    const int t = col0 / 192;
    uint* dst = (t == 0) ? qp : (t == 1) ? kp : vp;
    const float sc = (t == 0) ? kScale : 1.0f;
#pragma unroll
    for (int nt = 0; nt < 3; ++nt) {
      const int c0 = wn * 48 + nt * 16;
      const int hh = c0 >> 5;             // head, uniform per tile
      const int d0 = (c0 & 31) + rr;
      const float bcol = bias[col0 + c0 + rr];
#pragma unroll
      for (int mt = 0; mt < 4; ++mt)
#pragma unroll
        for (int reg = 0; reg < 4; ++reg) {
          const int grow = row0 + wm * 64 + mt * 16 + kg * 4 + reg;
          const int w = grow / 144;
          const int l = grow % 144;
          dst[(((size_t)(w * 6 + hh)) * 144 + l) * 32 + d0] =
              pack_hl((acc[mt][nt][reg] + bcol) * sc);
        }
    }
  } else {
#pragma unroll
    for (int nt = 0; nt < 3; ++nt) {
      const int c = wn * 48 + nt * 16 + rr;
      const float bcol = bias[c];
#pragma unroll
      for (int mt = 0; mt < 4; ++mt)
#pragma unroll
        for (int reg = 0; reg < 4; ++reg) {
          const int grow = row0 + wm * 64 + mt * 16 + kg * 4 + reg;
          fout[(size_t)grow * 192 + c] = acc[mt][nt][reg] + bcol;
        }
    }
  }
}

// ---------------------------------------------------------------------------
// attn unit body (R7's measured-best pipeline, 9 waves, wave == i-strip).
// ---------------------------------------------------------------------------
__device__ __forceinline__ void attn_unit(
    const ushort (&KsH)[144][40], const ushort (&KsL)[144][40],
    const ushort (&VtH)[32][168], const ushort (&VtL)[32][168],
    uint* __restrict__ scrw,
    const uint* __restrict__ qpb, const float* __restrict__ mrow,
    const float* __restrict__ brow, uint* __restrict__ aopb,
    int wave, int rr, int kg)
{
  const int i0 = wave * 16;
  const int i = i0 + rr;
  const int pi = 828 * (i / 72) + 23 * ((i / 12) % 6) + (i % 12) + 11;

  // preloads (overlap with surrounding work; no barrier between issue & use)
  const uint4 qa = *(const uint4*)&qpb[(size_t)i * 32 + kg * 8];
  const uint4 qb = *(const uint4*)&qpb[(size_t)i * 32 + kg * 8 + 4];
  float4 mv[9], bv[9];
#pragma unroll
  for (int jt = 0; jt < 9; ++jt) {
    const int jb = jt * 16 + kg * 4;
    mv[jt] = *(const float4*)&mrow[(size_t)i * 144 + jb];
    const int pjb = 1656 * (jb / 72) + 138 * ((jb / 12) % 6) - (jb % 12);
    bv[jt] = *(const float4*)&brow[pi + pjb - 3];  // {bb-3,bb-2,bb-1,bb}
  }

  union { short8 v; uint u[4]; } QH, QL;
  QH.u[0] = (qa.x >> 16) | (qa.y & 0xffff0000u);
  QH.u[1] = (qa.z >> 16) | (qa.w & 0xffff0000u);
  QH.u[2] = (qb.x >> 16) | (qb.y & 0xffff0000u);
  QH.u[3] = (qb.z >> 16) | (qb.w & 0xffff0000u);
  QL.u[0] = (qa.x & 0xffffu) | (qa.y << 16);
  QL.u[1] = (qa.z & 0xffffu) | (qa.w << 16);
  QL.u[2] = (qb.x & 0xffffu) | (qb.y << 16);
  QL.u[3] = (qb.z & 0xffffu) | (qb.w << 16);

  // Phase 1: S^T = K.Q^T + bias + mask; lane holds j-run for fixed i
  f32x4 acc[9];
#pragma unroll
  for (int jt = 0; jt < 9; ++jt) {
    const short8 kah = *(const short8*)&KsH[jt * 16 + rr][kg * 8];
    const short8 kal = *(const short8*)&KsL[jt * 16 + rr][kg * 8];
    f32x4 c = (f32x4){0.f, 0.f, 0.f, 0.f};
    c = __builtin_amdgcn_mfma_f32_16x16x32_bf16(kah, QH.v, c, 0, 0, 0);
    c = __builtin_amdgcn_mfma_f32_16x16x32_bf16(kah, QL.v, c, 0, 0, 0);
    c = __builtin_amdgcn_mfma_f32_16x16x32_bf16(kal, QH.v, c, 0, 0, 0);
    c[0] += bv[jt].w + mv[jt].x;
    c[1] += bv[jt].z + mv[jt].y;
    c[2] += bv[jt].y + mv[jt].z;
    c[3] += bv[jt].x + mv[jt].w;
    acc[jt] = c;
  }

  // Phase 2: in-register softmax (lanes {rr,rr+16,rr+32,rr+48} share i)
  float m = -1e30f;
#pragma unroll
  for (int jt = 0; jt < 9; ++jt)
    m = fmaxf(m, fmaxf(fmaxf(acc[jt][0], acc[jt][1]),
                       fmaxf(acc[jt][2], acc[jt][3])));
  m = fmaxf(m, __shfl_xor(m, 16));
  m = fmaxf(m, __shfl_xor(m, 32));
  float s = 0.f;
#pragma unroll
  for (int jt = 0; jt < 9; ++jt)
#pragma unroll
    for (int r = 0; r < 4; ++r) {
      acc[jt][r] = __expf(acc[jt][r] - m);
      s += acc[jt][r];
    }
  s += __shfl_xor(s, 16);
  s += __shfl_xor(s, 32);
  const float inv = 1.0f / s;

  uint wh_[10][2], wl_[10][2];  // jt 9 = zero pad (j in [144,160))
#pragma unroll
  for (int jt = 0; jt < 9; ++jt)
#pragma unroll
    for (int u = 0; u < 2; ++u) {
      const float p0 = acc[jt][2 * u] * inv, p1 = acc[jt][2 * u + 1] * inv;
      const ushort h0 = bf16_rne(p0), h1 = bf16_rne(p1);
      const ushort l0 = bf16_rne(p0 - bf16_to_f(h0));
      const ushort l1 = bf16_rne(p1 - bf16_to_f(h1));
      wh_[jt][u] = (uint)h0 | ((uint)h1 << 16);
      wl_[jt][u] = (uint)l0 | ((uint)l1 << 16);
    }
  wh_[9][0] = 0; wh_[9][1] = 0; wl_[9][0] = 0; wl_[9][1] = 0;

  // Phase 3: PV via per-wave transpose scratch (wave-lockstep ordering)
  f32x4 oacc[2] = {(f32x4){0.f, 0.f, 0.f, 0.f}, (f32x4){0.f, 0.f, 0.f, 0.f}};
#pragma unroll
  for (int ks = 0; ks < 5; ++ks) {
    const int jtA = 2 * ks, jtB = 2 * ks + 1;
    *(uint2*)&scrw[rr * 20 + 2 * kg]           = make_uint2(wh_[jtA][0], wh_[jtA][1]);
    *(uint2*)&scrw[rr * 20 + 8 + 2 * kg]       = make_uint2(wh_[jtB][0], wh_[jtB][1]);
    *(uint2*)&scrw[320 + rr * 20 + 2 * kg]     = make_uint2(wl_[jtA][0], wl_[jtA][1]);
    *(uint2*)&scrw[320 + rr * 20 + 8 + 2 * kg] = make_uint2(wl_[jtB][0], wl_[jtB][1]);
    asm volatile("s_waitcnt lgkmcnt(0)" ::: "memory");
    const ushort* scr = (const ushort*)scrw;
    const short8 pfh = *(const short8*)&scr[rr * 40 + kg * 8];
    const short8 pfl = *(const short8*)&scr[640 + rr * 40 + kg * 8];
#pragma unroll
    for (int dt = 0; dt < 2; ++dt) {
      const short8 vfh = *(const short8*)&VtH[dt * 16 + rr][ks * 32 + kg * 8];
      const short8 vfl = *(const short8*)&VtL[dt * 16 + rr][ks * 32 + kg * 8];
      oacc[dt] = __builtin_amdgcn_mfma_f32_16x16x32_bf16(pfh, vfh, oacc[dt], 0, 0, 0);
      oacc[dt] = __builtin_amdgcn_mfma_f32_16x16x32_bf16(pfh, vfl, oacc[dt], 0, 0, 0);
      oacc[dt] = __builtin_amdgcn_mfma_f32_16x16x32_bf16(pfl, vfh, oacc[dt], 0, 0, 0);
    }
    asm volatile("s_waitcnt lgkmcnt(0)" ::: "memory");
  }

  // epilogue: pack O hi/lo -> aop (uint per element, 64 B segments)
#pragma unroll
  for (int dt = 0; dt < 2; ++dt)
#pragma unroll
    for (int r = 0; r < 4; ++r)
      aopb[(size_t)(i0 + kg * 4 + r) * 192 + dt * 16 + rr] =
          pack_hl(oacc[dt][r]);
}

// K/V unpack-and-write helpers for staging a (l,d) slot from packed uint4s.
__device__ __forceinline__ void write_k(
    ushort (&KH)[144][40], ushort (&KL)[144][40], int l, int d, uint4 kv)
{
  ushort4 hk, lk;
  hk.x = (ushort)(kv.x >> 16); lk.x = (ushort)(kv.x & 0xffff);
  hk.y = (ushort)(kv.y >> 16); lk.y = (ushort)(kv.y & 0xffff);
  hk.z = (ushort)(kv.z >> 16); lk.z = (ushort)(kv.z & 0xffff);
  hk.w = (ushort)(kv.w >> 16); lk.w = (ushort)(kv.w & 0xffff);
  *(ushort4*)&KH[l][d] = hk;
  *(ushort4*)&KL[l][d] = lk;
}
__device__ __forceinline__ void write_vt(
    ushort (&VH)[32][168], ushort (&VL)[32][168], int l, int d, uint4 vv)
{
  VH[d + 0][l] = (ushort)(vv.x >> 16); VL[d + 0][l] = (ushort)(vv.x & 0xffff);
  VH[d + 1][l] = (ushort)(vv.y >> 16); VL[d + 1][l] = (ushort)(vv.y & 0xffff);
  VH[d + 2][l] = (ushort)(vv.z >> 16); VL[d + 2][l] = (ushort)(vv.z & 0xffff);
  VH[d + 3][l] = (ushort)(vv.w >> 16); VL[d + 3][l] = (ushort)(vv.w & 0xffff);
}

// ---------------------------------------------------------------------------
// attn: 1440 blocks x 576 thr. Block b -> q=(b&7)*180+(b>>3); window w=q>>1,
// heads h0..h0+2 (h0=(q&1)*3). 3-deep sequential pipeline, ring of 3 LDS
// buffers; unit u+1's K/V in regs during unit u's compute. LDS 156.7 KB.
// ---------------------------------------------------------------------------
__global__ __launch_bounds__(576) void attn_kernel(
    const uint* __restrict__ qp, const uint* __restrict__ kp,
    const uint* __restrict__ vp, const float* __restrict__ mask,
    const float* __restrict__ btT, uint* __restrict__ aop)
{
  __shared__ __align__(16) ushort Ks_[3][2][144][40];  // [buf][hi/lo]
  __shared__ __align__(16) ushort Vt[3][2][32][168];   // [buf][hi/lo][d][j]
  __shared__ __align__(16) uint Scr[9][640];           // per-wave PV scratch

  const int tid = threadIdx.x;
  const int wave = tid >> 6, lane = tid & 63;
  const int rr = lane & 15, kg = lane >> 4;

  const int b = blockIdx.x;
  const int q = (b & 7) * 180 + (b >> 3);  // bijective: 1440 = 8*180
  const int w = q >> 1;                    // window
  const int h0 = (q & 1) * 3;              // heads h0, h0+1, h0+2
  const size_t base0 = (size_t)(w * 6 + h0) * 4608;
  const float* mrow = mask + (size_t)w * 20736;
  const float* brow0 = btT + (size_t)((w % 240) * 6 + h0) * 3312;
  uint* aopb0 = aop + (size_t)w * 144 * 192 + h0 * 32;

  const int l0 = tid >> 3, d0 = (tid & 7) * 4;
  const int f1 = tid + 576;
  const int l1 = f1 >> 3, d1 = (f1 & 7) * 4;

  // --- stage unit0 K/Vt into buf0 (direct) ---
  {
    const uint4 kvA = *(const uint4*)&kp[base0 + l0 * 32 + d0];
    const uint4 vvA = *(const uint4*)&vp[base0 + l0 * 32 + d0];
    const uint4 kvB = *(const uint4*)&kp[base0 + l1 * 32 + d1];
    const uint4 vvB = *(const uint4*)&vp[base0 + l1 * 32 + d1];
    write_k(Ks_[0][0], Ks_[0][1], l0, d0, kvA);
    write_k(Ks_[0][0], Ks_[0][1], l1, d1, kvB);
    write_vt(Vt[0][0], Vt[0][1], l0, d0, vvA);
    write_vt(Vt[0][0], Vt[0][1], l1, d1, vvB);
  }
  // zero-pad j in [144,160) for ALL 3 buffers & planes (3072 slots)
  for (int f = tid; f < 3072; f += 576) {
    const int bu = f >> 10, pl = (f >> 9) & 1, d = (f >> 4) & 31, j = 144 + (f & 15);
    Vt[bu][pl][d][j] = 0;
  }

  // --- issue unit1 K/V loads (consumed after unit0 compute) ---
  uint4 kA = *(const uint4*)&kp[base0 + 4608 + l0 * 32 + d0];
  uint4 vA = *(const uint4*)&vp[base0 + 4608 + l0 * 32 + d0];
  uint4 kB = *(const uint4*)&kp[base0 + 4608 + l1 * 32 + d1];
  uint4 vB = *(const uint4*)&vp[base0 + 4608 + l1 * 32 + d1];

  __syncthreads();  // buf0 ready

  // --- unit0 compute ---
  attn_unit(Ks_[0][0], Ks_[0][1], Vt[0][0], Vt[0][1], Scr[wave],
            qp + base0, mrow, brow0, aopb0, wave, rr, kg);

  // --- write unit1 regs -> buf1; issue unit2 loads ---
  write_k(Ks_[1][0], Ks_[1][1], l0, d0, kA);
  write_k(Ks_[1][0], Ks_[1][1], l1, d1, kB);
  write_vt(Vt[1][0], Vt[1][1], l0, d0, vA);
  write_vt(Vt[1][0], Vt[1][1], l1, d1, vB);
  kA = *(const uint4*)&kp[base0 + 9216 + l0 * 32 + d0];
  vA = *(const uint4*)&vp[base0 + 9216 + l0 * 32 + d0];
  kB = *(const uint4*)&kp[base0 + 9216 + l1 * 32 + d1];
  vB = *(const uint4*)&vp[base0 + 9216 + l1 * 32 + d1];

  __syncthreads();  // buf1 ready

  // --- unit1 compute ---
  attn_unit(Ks_[1][0], Ks_[1][1], Vt[1][0], Vt[1][1], Scr[wave],
            qp + base0 + 4608, mrow, brow0 + 3312, aopb0 + 32, wave, rr, kg);

  // --- write unit2 regs -> buf2 ---
  write_k(Ks_[2][0], Ks_[2][1], l0, d0, kA);
  write_k(Ks_[2][0], Ks_[2][1], l1, d1, kB);
  write_vt(Vt[2][0], Vt[2][1], l0, d0, vA);
  write_vt(Vt[2][0], Vt[2][1], l1, d1, vB);

  __syncthreads();  // buf2 ready

  // --- unit2 compute ---
  attn_unit(Ks_[2][0], Ks_[2][1], Vt[2][0], Vt[2][1], Scr[wave],
            qp + base0 + 9216, mrow, brow0 + 6624, aopb0 + 64, wave, rr, kg);
}

// ---------------------------------------------------------------------------
extern "C" void kernel_launch(void* const* d_in, const int* in_sizes, int n_in,
                              void* d_out, int out_size, void* d_ws, size_t ws_size,
                              hipStream_t stream)
{
  const float* x    = (const float*)d_in[0];  // (720,144,192)
  const float* mask = (const float*)d_in[1];  // (720,144,144)
  const float* w1   = (const float*)d_in[2];  // (576,192)
  const float* b1   = (const float*)d_in[3];  // (576,)
  const float* w2   = (const float*)d_in[4];  // (192,192)
  const float* b2   = (const float*)d_in[5];  // (192,)
  const float* bt   = (const float*)d_in[6];  // (3312,240,6)
  float* out = (float*)d_out;

  // ws layout: 4 packed-uint tensors x 19,906,560 x 4 B = 318,504,960 B exact.
  uint* qp  = (uint*)d_ws;
  uint* kp  = qp + kQKVElems;
  uint* vp  = kp + kQKVElems;
  uint* aop = vp + kQKVElems;
  // w1 planes in dead aop region (qkv reads them before attn writes aop)
  ushort* w1h = (ushort*)aop;
  ushort* w1l = w1h + 110592;
  // w2 planes in dead qp region (prep2 runs after attn)
  ushort* w2h = (ushort*)qp;
  ushort* w2l = w2h + 36864;
  // transposed bias table in dead d_out region (proj overwrites at the end)
  float* btT = out;  // (1440, 3312) = 19.1 MB < 79.6 MB

  btT_kernel<<<69 * 30, 256, 0, stream>>>(bt, btT);
  prep_kernel<<<432, 256, 0, stream>>>(w1, w1h, w1l, 110592);
  gemm_kernel<true><<<810 * 3, 512, 0, stream>>>(
      x, nullptr, w1h, w1l, b1, qp, kp, vp, nullptr);
  attn_kernel<<<1440, 576, 0, stream>>>(qp, kp, vp, mask, btT, aop);
  prep_kernel<<<144, 256, 0, stream>>>(w2, w2h, w2l, 36864);
  gemm_kernel<false><<<810, 512, 0, stream>>>(
      nullptr, aop, w2h, w2l, b2, nullptr, nullptr, nullptr, out);
}